// Round 5
// baseline (481.628 us; speedup 1.0000x reference)
//
#include <hip/hip_runtime.h>

#define N_NODES 50000
#define N_EDGES 500000
#define D_NODE 64
#define D_EDGE 32
#define MSG_DIM 160
#define HID_DIM 224
#define ALPHA 0.01f

#define FNB 16          // nodes per fused block (50000 = 3125 * 16 exactly)
#define NBKT 3125       // node buckets = fused grid size
#define BKT_CAP 256     // fixed capacity per bucket (mean 160, +7.6 sigma headroom)
#define MS_STRIDE 164   // m_sum f32 row stride (160 + 4 pad, 16B-aligned rows)
#define MT_STRIDE 40    // per-wave transpose buffer: 32 edges + 8 pad (shorts)
#define CURSOR_PAD 16   // ints per bucket cursor (64B line -> no line contention)
#define CVT_BLKS 3200   // ceil(818944/256)
#define SCAT_BLKS 1954  // ceil(500000/256)

typedef unsigned short u16;
typedef unsigned long long u64;
typedef short short8 __attribute__((ext_vector_type(8)));
typedef float float4v __attribute__((ext_vector_type(4)));

static __device__ __forceinline__ u16 f2bf(float f) {
    unsigned int u = __float_as_uint(f);
    u += 0x7fffu + ((u >> 16) & 1u);   // round-to-nearest-even
    return (u16)(u >> 16);
}

// fused: bf16 conversion of h_n/W_msg/W_hid (blocks 0..3199) + direct
// fixed-capacity bucket scatter (blocks 3200..). R1-proven; effectively free
// (R4 showed fixed harness gap ~121us absorbs these dispatches).
__global__ __launch_bounds__(256) void cvt_scatter(const float* __restrict__ h_n,
                                                   const float* __restrict__ W_msg,
                                                   const float* __restrict__ W_hid,
                                                   const int* __restrict__ src,
                                                   const int* __restrict__ dst,
                                                   u16* __restrict__ hn_bf,
                                                   u16* __restrict__ Wm_bf,
                                                   u16* __restrict__ Wh_bf,
                                                   int* __restrict__ cursor,
                                                   u64* __restrict__ pack) {
    const int b = blockIdx.x;
    if (b < CVT_BLKS) {
        int i = b * 256 + threadIdx.x;
        const float* in; u16* outp; int j;
        if (i < 800000)      { in = h_n;   outp = hn_bf; j = i; }
        else if (i < 806400) { in = W_msg; outp = Wm_bf; j = i - 800000; }
        else if (i < 818944) { in = W_hid; outp = Wh_bf; j = i - 806400; }
        else return;
        float4 v = reinterpret_cast<const float4*>(in)[j];
        ushort4 o;
        o.x = f2bf(v.x); o.y = f2bf(v.y); o.z = f2bf(v.z); o.w = f2bf(v.w);
        reinterpret_cast<ushort4*>(outp)[j] = o;
    } else {
        int e = (b - CVT_BLKS) * 256 + threadIdx.x;
        if (e < N_EDGES) {
            int d = dst[e];
            int bk = d >> 4;
            int idx = atomicAdd(&cursor[bk * CURSOR_PAD], 1);
            if (idx < BKT_CAP)   // memory-safety guard; statistically never taken
                pack[(size_t)bk * BKT_CAP + idx] =
                    ((u64)e << 34) | ((u64)d << 17) | (u64)src[e];
        }
    }
}

// ---------------- fused kernel: wave-autonomous phase 1 ----------------
// Block b owns nodes [16b,16b+16) = pack[b*256, b*256+count_b).
// Wave w processes edge groups [w*32, w*32+32) stride 128 INDEPENDENTLY:
//   per-lane direct global gathers of MFMA A-frags (one wave per edge, no
//   redundancy), all 10 f-chunks per wave, wave-private MT transpose (ds ops
//   within a wave need no barrier), reduce-MFMA into per-wave m_acc[10].
// ZERO __syncthreads in the edge loop. Cross-wave combine = one LDS f32
// atomicAdd pass + one barrier, then the proven phase-2 update GEMM.
__global__ __launch_bounds__(256) void fused_kernel(
    const u16* __restrict__ hn_bf, const float* __restrict__ h_e,
    const u64* __restrict__ pack, const int* __restrict__ cursor,
    const u16* __restrict__ Wm_bf, const float* __restrict__ b_msg,
    const u16* __restrict__ Wh_bf, const float* __restrict__ b_hid,
    float* __restrict__ out)
{
    __shared__ alignas(16) float m_sum[FNB * MS_STRIDE];   // 10496 B
    __shared__ alignas(16) u16 MT[4 * 16 * MT_STRIDE];     //  5120 B -> 15.6 KB

    const int tid = threadIdx.x;
    const int n0 = blockIdx.x * FNB;
    const int p_begin = blockIdx.x * BKT_CAP;
    int ecnt = cursor[blockIdx.x * CURSOR_PAD];
    if (ecnt > BKT_CAP) ecnt = BKT_CAP;
    const int p_end = p_begin + ecnt;

    const int wave = tid >> 6, lane = tid & 63;
    const int qd = lane >> 4, l15 = lane & 15;
    const int myrow = n0 + l15;            // dst node this lane selects for
    u16* MTw = &MT[wave * 16 * MT_STRIDE];

    // zero the f32 accumulation tile
    for (int i = tid; i < FNB * MS_STRIDE; i += 256) m_sum[i] = 0.f;

    // per-lane bias for f = c*16 + l15 (static index -> registers)
    float biasv[10];
#pragma unroll
    for (int c = 0; c < 10; ++c) biasv[c] = b_msg[c * 16 + l15];

    float4v m_acc[10];
#pragma unroll
    for (int c = 0; c < 10; ++c) m_acc[c] = (float4v){0.f, 0.f, 0.f, 0.f};

    __syncthreads();   // m_sum zeroed before any wave's atomics

    // ---------------- phase 1: per-wave 32-edge groups, no barriers --------
    for (int p0 = p_begin + wave * 32; p0 < p_end; p0 += 128) {
        // A-frags: xf[g][ks] = X[e = g*16 + l15][k = ks*32 + qd*8 .. +8]
        // (each 16B fragment is contiguous in global memory)
        short8 xf[2][5];
#pragma unroll
        for (int g = 0; g < 2; ++g) {
            int x = p0 + g * 16 + l15;
            if (x > p_end - 1) x = p_end - 1;      // clamp pads (S masks them)
            const u64 pk = pack[x];
            const int sr = (int)(pk & 0x1FFFF);
            const int dr = (int)((pk >> 17) & 0x1FFFF);
            const int eo = (int)(pk >> 34);
            const short8* srow = reinterpret_cast<const short8*>(
                hn_bf + (size_t)sr * D_NODE + qd * 8);
            xf[g][0] = srow[0];                    // k in [0,64): h_n[src]
            xf[g][1] = srow[4];
            const short8* drow = reinterpret_cast<const short8*>(
                hn_bf + (size_t)dr * D_NODE + qd * 8);
            xf[g][2] = drow[0];                    // k in [64,128): h_n[dst]
            xf[g][3] = drow[4];
            const float4* he = reinterpret_cast<const float4*>(
                h_e + (size_t)eo * D_EDGE + qd * 8);
            float4 ha = he[0], hb = he[1];
            short8 t;
            t[0] = (short)f2bf(ha.x); t[1] = (short)f2bf(ha.y);
            t[2] = (short)f2bf(ha.z); t[3] = (short)f2bf(ha.w);
            t[4] = (short)f2bf(hb.x); t[5] = (short)f2bf(hb.y);
            t[6] = (short)f2bf(hb.z); t[7] = (short)f2bf(hb.w);
            xf[g][4] = t;                          // k in [128,160): h_e
        }

        // selection frag S[n=l15][e=qd*8+j] (bf16 1.0/0.0), contiguous pack
        short8 a2;
        {
            const int xb = p0 + qd * 8;
            const int nv = p_end - xb;             // valid among my 8
#pragma unroll
            for (int j = 0; j < 8; ++j) {
                int idx = xb + j;
                if (idx > p_end - 1) idx = p_end - 1;
                const u64 pk = pack[idx];
                const int dr = (int)((pk >> 17) & 0x1FFFF);
                a2[j] = (short)((j < nv && dr == myrow) ? 0x3F80 : 0);
            }
        }

        // 10 f-chunks: M-build MFMAs -> wave-private transpose -> reduce MFMA
#pragma unroll
        for (int c = 0; c < 10; ++c) {
            short8 wf[5];
#pragma unroll
            for (int ks = 0; ks < 5; ++ks)         // W rows from L1/L2 (hot)
                wf[ks] = *reinterpret_cast<const short8*>(
                    Wm_bf + (size_t)(c * 16 + l15) * MSG_DIM + ks * 32 + qd * 8);
            const float bias = biasv[c];
#pragma unroll
            for (int g = 0; g < 2; ++g) {
                float4v acc = {0.f, 0.f, 0.f, 0.f};
#pragma unroll
                for (int ks = 0; ks < 5; ++ks)
                    acc = __builtin_amdgcn_mfma_f32_16x16x32_bf16(xf[g][ks], wf[ks], acc, 0, 0, 0);
                // D[e=g*16+qd*4+r][f=c*16+l15]; bias + leaky
                float v0 = acc[0] + bias, v1 = acc[1] + bias,
                      v2 = acc[2] + bias, v3 = acc[3] + bias;
                v0 = fmaxf(v0, ALPHA * v0); v1 = fmaxf(v1, ALPHA * v1);
                v2 = fmaxf(v2, ALPHA * v2); v3 = fmaxf(v3, ALPHA * v3);
                ushort4 m4;
                m4.x = f2bf(v0); m4.y = f2bf(v1); m4.z = f2bf(v2); m4.w = f2bf(v3);
                // MT[f=l15][e=g*16+qd*4 ..+3]
                *reinterpret_cast<ushort4*>(&MTw[l15 * MT_STRIDE + g * 16 + qd * 4]) = m4;
            }
            // reduce: m_acc[c] += S x M  (B[k=e=qd*8+j][col=f=l15])
            short8 b2 = *reinterpret_cast<const short8*>(&MTw[l15 * MT_STRIDE + qd * 8]);
            m_acc[c] = __builtin_amdgcn_mfma_f32_16x16x32_bf16(a2, b2, m_acc[c], 0, 0, 0);
        }
    }

    // cross-wave combine: partial m_sum[n=qd*4+r][f=c*16+l15] += m_acc
#pragma unroll
    for (int c = 0; c < 10; ++c)
#pragma unroll
        for (int r = 0; r < 4; ++r)
            atomicAdd(&m_sum[(qd * 4 + r) * MS_STRIDE + c * 16 + l15], m_acc[c][r]);
    __syncthreads();                       // combine complete

    // ---------------- phase 2: update GEMM ----------------
    const int node = n0 + l15;             // exact (50000 = 3125*16)
    short8 b_frag[7];
#pragma unroll
    for (int ks = 0; ks < 5; ++ks) {       // k in [0,160): m_sum (f32 -> bf16)
        const float4* mrow = reinterpret_cast<const float4*>(
            &m_sum[l15 * MS_STRIDE + ks * 32 + qd * 8]);
        float4 ma = mrow[0], mb = mrow[1];
        short8 t;
        t[0] = (short)f2bf(ma.x); t[1] = (short)f2bf(ma.y);
        t[2] = (short)f2bf(ma.z); t[3] = (short)f2bf(ma.w);
        t[4] = (short)f2bf(mb.x); t[5] = (short)f2bf(mb.y);
        t[6] = (short)f2bf(mb.z); t[7] = (short)f2bf(mb.w);
        b_frag[ks] = t;
    }
#pragma unroll
    for (int ks = 5; ks < 7; ++ks)         // k in [160,224): h_n (bf16)
        b_frag[ks] = *reinterpret_cast<const short8*>(
            hn_bf + (size_t)node * D_NODE + (ks - 5) * 32 + qd * 8);

    for (int c = wave; c < 14; c += 4) {   // waves split 14 feature chunks
        float4v acc = {0.f, 0.f, 0.f, 0.f};
#pragma unroll
        for (int ks = 0; ks < 7; ++ks) {
            short8 a = *reinterpret_cast<const short8*>(
                Wh_bf + (size_t)(c * 16 + l15) * HID_DIM + ks * 32 + qd * 8);
            acc = __builtin_amdgcn_mfma_f32_16x16x32_bf16(a, b_frag[ks], acc, 0, 0, 0);
        }
        const float4 bias = *reinterpret_cast<const float4*>(b_hid + c * 16 + qd * 4);
        float v0 = acc[0] + bias.x, v1 = acc[1] + bias.y,
              v2 = acc[2] + bias.z, v3 = acc[3] + bias.w;
        v0 = fmaxf(v0, ALPHA * v0); v1 = fmaxf(v1, ALPHA * v1);
        v2 = fmaxf(v2, ALPHA * v2); v3 = fmaxf(v3, ALPHA * v3);
        float4 o; o.x = v0; o.y = v1; o.z = v2; o.w = v3;
        *reinterpret_cast<float4*>(&out[(size_t)node * HID_DIM + c * 16 + qd * 4]) = o;
    }
}

extern "C" void kernel_launch(void* const* d_in, const int* in_sizes, int n_in,
                              void* d_out, int out_size, void* d_ws, size_t ws_size,
                              hipStream_t stream)
{
    const float* h_n   = (const float*)d_in[0];
    const float* h_e   = (const float*)d_in[1];
    const int*   src   = (const int*)d_in[2];
    const int*   dst   = (const int*)d_in[3];
    const float* W_msg = (const float*)d_in[4];
    const float* b_msg = (const float*)d_in[5];
    const float* W_hid = (const float*)d_in[6];
    const float* b_hid = (const float*)d_in[7];
    float* out = (float*)d_out;

    char* ws = (char*)d_ws;
    u16* hn_bf  = (u16*)(ws + 0);                    //  6,400,000 B
    u16* Wm_bf  = (u16*)(ws + 6400000);              //     51,200 B
    u16* Wh_bf  = (u16*)(ws + 6451200);              //    100,352 B
    int* cursor = (int*)(ws + 6551552);              //    200,000 B (3125 x 16 ints)
    u64* pack   = (u64*)(ws + 6751552);              //  6,400,000 B (~13.2 MB total)

    hipMemsetAsync(cursor, 0, (size_t)NBKT * CURSOR_PAD * sizeof(int), stream);
    cvt_scatter<<<CVT_BLKS + SCAT_BLKS, 256, 0, stream>>>(
        h_n, W_msg, W_hid, src, dst, hn_bf, Wm_bf, Wh_bf, cursor, pack);
    fused_kernel<<<NBKT, 256, 0, stream>>>(
        hn_bf, h_e, pack, cursor, Wm_bf, b_msg, Wh_bf, b_hid, out);
}

// Round 7
// 284.690 us; speedup vs baseline: 1.6918x; 1.6918x over previous
//
#include <hip/hip_runtime.h>

#define N_NODES 50000
#define N_EDGES 500000
#define D_NODE 64
#define D_EDGE 32
#define MSG_DIM 160
#define HID_DIM 224
#define ALPHA 0.01f

#define FNB 32          // nodes per fused block (ceil(50000/32) = 1563 buckets)
#define NBKT 1563       // node buckets = fused grid size (last bucket: 16 nodes)
#define BKT_CAP 512     // fixed capacity per bucket (mean 320, sigma 17.9 -> 10.7 sigma)
#define A_STRIDE 168    // 160 + 8 pad (shorts) -> conflict-free b128 frag reads
#define MT_STRIDE 72    // 64 edges + 8 pad (shorts), per-wave transpose buffer
#define CURSOR_PAD 16   // ints per bucket cursor (64B line -> no line contention)
#define CVT_BLKS 3200   // ceil(818944/256)
#define SCAT_BLKS 1954  // ceil(500000/256)

typedef unsigned short u16;
typedef unsigned long long u64;
typedef short short8 __attribute__((ext_vector_type(8)));
typedef float float4v __attribute__((ext_vector_type(4)));

static __device__ __forceinline__ u16 f2bf(float f) {
    unsigned int u = __float_as_uint(f);
    u += 0x7fffu + ((u >> 16) & 1u);   // round-to-nearest-even
    return (u16)(u >> 16);
}

// fused: bf16 conversion of h_n/W_msg/W_hid (blocks 0..3199) + direct
// fixed-capacity bucket scatter (blocks 3200..). No histogram, no scan.
__global__ __launch_bounds__(256) void cvt_scatter(const float* __restrict__ h_n,
                                                   const float* __restrict__ W_msg,
                                                   const float* __restrict__ W_hid,
                                                   const int* __restrict__ src,
                                                   const int* __restrict__ dst,
                                                   u16* __restrict__ hn_bf,
                                                   u16* __restrict__ Wm_bf,
                                                   u16* __restrict__ Wh_bf,
                                                   int* __restrict__ cursor,
                                                   u64* __restrict__ pack) {
    const int b = blockIdx.x;
    if (b < CVT_BLKS) {
        int i = b * 256 + threadIdx.x;
        const float* in; u16* outp; int j;
        if (i < 800000)      { in = h_n;   outp = hn_bf; j = i; }
        else if (i < 806400) { in = W_msg; outp = Wm_bf; j = i - 800000; }
        else if (i < 818944) { in = W_hid; outp = Wh_bf; j = i - 806400; }
        else return;
        float4 v = reinterpret_cast<const float4*>(in)[j];
        ushort4 o;
        o.x = f2bf(v.x); o.y = f2bf(v.y); o.z = f2bf(v.z); o.w = f2bf(v.w);
        reinterpret_cast<ushort4*>(outp)[j] = o;
    } else {
        int e = (b - CVT_BLKS) * 256 + threadIdx.x;
        if (e < N_EDGES) {
            int d = dst[e];
            int bk = d >> 5;                       // FNB = 32
            int idx = atomicAdd(&cursor[bk * CURSOR_PAD], 1);
            if (idx < BKT_CAP)   // memory-safety guard; statistically never taken
                pack[(size_t)bk * BKT_CAP + idx] =
                    ((u64)e << 34) | ((u64)d << 17) | (u64)src[e];
        }
    }
}

// ---------------- fused kernel: msg GEMM -> MFMA-based segment reduce -> update GEMM
// Block b owns nodes [32b,32b+32) = pack[b*512, b*512+count_b)  (~320 edges,
// ~5 tiles/block vs R1's 2.5 -> per-block fixed costs halved: prologue,
// phase-2 setup, Wm/Wh L1 warm-up, drain). Tile pipeline identical to the
// proven R0/R1 structure (direct staging; register prefetch removed - R1
// showed it null, and dropping it frees ~26 VGPRs to pay for the 32-node
// reduce state m_acc[3][2]).
__global__ __launch_bounds__(256) void fused_kernel(
    const u16* __restrict__ hn_bf, const float* __restrict__ h_e,
    const u64* __restrict__ pack, const int* __restrict__ cursor,
    const u16* __restrict__ Wm_bf, const float* __restrict__ b_msg,
    const u16* __restrict__ Wh_bf, const float* __restrict__ b_hid,
    float* __restrict__ out)
{
    __shared__ alignas(16) u16 X_lds[64 * A_STRIDE];        // 21504 B (Xb in ph2)
    __shared__ alignas(16) u16 MT[4 * 16 * MT_STRIDE];      //  9216 B (per-wave)
    __shared__ alignas(16) u16 dst16[64];                   //   128 B  -> ~30.9 KB

    const int tid = threadIdx.x;
    const int n0 = blockIdx.x * FNB;
    const int p_begin = blockIdx.x * BKT_CAP;
    int ecnt = cursor[blockIdx.x * CURSOR_PAD];
    if (ecnt > BKT_CAP) ecnt = BKT_CAP;
    const int p_end = p_begin + ecnt;

    const int wave = tid >> 6, lane = tid & 63;
    const int qd = lane >> 4, l15 = lane & 15;
    const int e_loc = tid >> 2, j4 = tid & 3;

    // per-lane bias for the wave's chunks {w, w+4, w+8} (<10)
    float biasv[3];
#pragma unroll
    for (int ci = 0; ci < 3; ++ci) {
        const int c = wave + ci * 4;
        biasv[ci] = (c < 10) ? b_msg[c * 16 + l15] : 0.f;
    }
    // m_acc[chunk][node-half]: D[n = h*16 + qd*4+r][f = c*16+l15]
    float4v m_acc[3][2];
#pragma unroll
    for (int ci = 0; ci < 3; ++ci) {
        m_acc[ci][0] = (float4v){0.f, 0.f, 0.f, 0.f};
        m_acc[ci][1] = (float4v){0.f, 0.f, 0.f, 0.f};
    }
    u16* MTw = &MT[wave * 16 * MT_STRIDE];

    // ---------------- phase 1: edge tiles ----------------
    for (int p0 = p_begin; p0 < p_end; p0 += 64) {
        {   // stage 64 bucketed edges x 160 bf16 (4 threads per edge)
            int pp = p0 + e_loc;
            const bool padE = (pp >= p_end); if (padE) pp = p_end - 1;
            const u64 pk = pack[pp];
            const int s  = (int)(pk & 0x1FFFF);
            const int d  = (int)((pk >> 17) & 0x1FFFF);
            const int eo = (int)(pk >> 34);
            if (j4 == 0) dst16[e_loc] = padE ? (u16)0xFFFFu : (u16)(d - n0);
            const uint4* srow = reinterpret_cast<const uint4*>(hn_bf + (size_t)s * D_NODE);
            const uint4* drow = reinterpret_cast<const uint4*>(hn_bf + (size_t)d * D_NODE);
            uint4* Arow = reinterpret_cast<uint4*>(&X_lds[e_loc * A_STRIDE]);
            Arow[j4 * 2]     = srow[j4 * 2];        // bf16 [0,64): h_n[src]
            Arow[j4 * 2 + 1] = srow[j4 * 2 + 1];
            Arow[8 + j4 * 2]     = drow[j4 * 2];    // bf16 [64,128): h_n[dst]
            Arow[8 + j4 * 2 + 1] = drow[j4 * 2 + 1];
            const float4* he = reinterpret_cast<const float4*>(h_e + (size_t)eo * D_EDGE);
            float4 p = he[j4 * 2], q = he[j4 * 2 + 1];
            ushort4 lo, hi;
            lo.x = f2bf(p.x); lo.y = f2bf(p.y); lo.z = f2bf(p.z); lo.w = f2bf(p.w);
            hi.x = f2bf(q.x); hi.y = f2bf(q.y); hi.z = f2bf(q.z); hi.w = f2bf(q.w);
            ushort4* Aus = reinterpret_cast<ushort4*>(Arow);
            Aus[32 + j4 * 2]     = lo;             // bf16 [128,160): h_e
            Aus[32 + j4 * 2 + 1] = hi;
        }
        __syncthreads();   // stage visible

        // x-frags for ALL 64 edges (A operand: lane=edge row, k=qd*8+j)
        short8 xf[4][5];
#pragma unroll
        for (int s = 0; s < 4; ++s)
#pragma unroll
            for (int ks = 0; ks < 5; ++ks)
                xf[s][ks] = *reinterpret_cast<const short8*>(
                    &X_lds[(s * 16 + l15) * A_STRIDE + ks * 32 + qd * 8]);

        // selection frags S[n = h*16 + l15][e = fi*32 + qd*8 + j] (bf16 1/0)
        short8 a2[2][2];
#pragma unroll
        for (int fi = 0; fi < 2; ++fi) {
            short8 dv = *reinterpret_cast<const short8*>(&dst16[fi * 32 + qd * 8]);
#pragma unroll
            for (int h = 0; h < 2; ++h) {
                const int want = h * 16 + l15;
                short8 t;
#pragma unroll
                for (int j = 0; j < 8; ++j)
                    t[j] = (short)(((int)(u16)dv[j] == want) ? 0x3F80 : 0);
                a2[fi][h] = t;
            }
        }
        __syncthreads();   // all frag reads done -> next stage may overwrite

        // MFMA chunk phase
#pragma unroll
        for (int ci = 0; ci < 3; ++ci) {
            const int c = wave + ci * 4;
            if (c >= 10) break;
            const int fbase = c * 16;
            short8 wf[5];
#pragma unroll
            for (int ks = 0; ks < 5; ++ks)       // W rows from L1/L2 (hot)
                wf[ks] = *reinterpret_cast<const short8*>(
                    Wm_bf + (size_t)(fbase + l15) * MSG_DIM + ks * 32 + qd * 8);
            const float bias = biasv[ci];
#pragma unroll
            for (int s = 0; s < 4; ++s) {        // 16-edge subtiles
                float4v acc = {0.f, 0.f, 0.f, 0.f};
#pragma unroll
                for (int ks = 0; ks < 5; ++ks)
                    acc = __builtin_amdgcn_mfma_f32_16x16x32_bf16(xf[s][ks], wf[ks], acc, 0, 0, 0);
                // D[e=qd*4+r][f=fbase+l15]; bias+leaky (leaky == max(x, a*x))
                float v0 = acc[0] + bias, v1 = acc[1] + bias,
                      v2 = acc[2] + bias, v3 = acc[3] + bias;
                v0 = fmaxf(v0, ALPHA * v0); v1 = fmaxf(v1, ALPHA * v1);
                v2 = fmaxf(v2, ALPHA * v2); v3 = fmaxf(v3, ALPHA * v3);
                ushort4 m4;
                m4.x = f2bf(v0); m4.y = f2bf(v1); m4.z = f2bf(v2); m4.w = f2bf(v3);
                // transpose via wave-private LDS: MT[f=l15][e=s*16+qd*4 ..+3]
                *reinterpret_cast<ushort4*>(&MTw[l15 * MT_STRIDE + s * 16 + qd * 4]) = m4;
            }
            // reduce: m_acc[ci][h] += S_h x M  (B operand: lane=f col, k=edge)
            short8 b2_0 = *reinterpret_cast<const short8*>(&MTw[l15 * MT_STRIDE + qd * 8]);
            short8 b2_1 = *reinterpret_cast<const short8*>(&MTw[l15 * MT_STRIDE + 32 + qd * 8]);
            m_acc[ci][0] = __builtin_amdgcn_mfma_f32_16x16x32_bf16(a2[0][0], b2_0, m_acc[ci][0], 0, 0, 0);
            m_acc[ci][0] = __builtin_amdgcn_mfma_f32_16x16x32_bf16(a2[1][0], b2_1, m_acc[ci][0], 0, 0, 0);
            m_acc[ci][1] = __builtin_amdgcn_mfma_f32_16x16x32_bf16(a2[0][1], b2_0, m_acc[ci][1], 0, 0, 0);
            m_acc[ci][1] = __builtin_amdgcn_mfma_f32_16x16x32_bf16(a2[1][1], b2_1, m_acc[ci][1], 0, 0, 0);
        }
    }
    __syncthreads();       // phase-1 X_lds use complete

    // ---------------- phase 2: write m_acc -> bf16 LDS, update GEMM ----------
    u16* Xb = X_lds;       // reuse as [32 nodes][A_STRIDE] bf16 (10.75 KB < 21.5)
#pragma unroll
    for (int ci = 0; ci < 3; ++ci) {
        const int c = wave + ci * 4;
        if (c >= 10) break;
#pragma unroll
        for (int h = 0; h < 2; ++h)
#pragma unroll
            for (int r = 0; r < 4; ++r)        // D[n=h*16+qd*4+r][f=c*16+l15]
                Xb[(h * 16 + qd * 4 + r) * A_STRIDE + c * 16 + l15] =
                    f2bf(m_acc[ci][h][r]);
    }
    __syncthreads();

#pragma unroll
    for (int h = 0; h < 2; ++h) {              // two 16-node groups
        const int node = n0 + h * 16 + l15;
        const int rnode = (node < N_NODES) ? node : (N_NODES - 1);  // clamp reads
        short8 b_frag[7];
#pragma unroll
        for (int ks = 0; ks < 5; ++ks)         // k in [0,160): m_sum (bf16)
            b_frag[ks] = *reinterpret_cast<const short8*>(
                &Xb[(h * 16 + l15) * A_STRIDE + ks * 32 + qd * 8]);
#pragma unroll
        for (int ks = 5; ks < 7; ++ks)         // k in [160,224): h_n (bf16)
            b_frag[ks] = *reinterpret_cast<const short8*>(
                hn_bf + (size_t)rnode * D_NODE + (ks - 5) * 32 + qd * 8);

        for (int c = wave; c < 14; c += 4) {   // waves split 14 feature chunks
            float4v acc = {0.f, 0.f, 0.f, 0.f};
#pragma unroll
            for (int ks = 0; ks < 7; ++ks) {
                short8 a = *reinterpret_cast<const short8*>(
                    Wh_bf + (size_t)(c * 16 + l15) * HID_DIM + ks * 32 + qd * 8);
                acc = __builtin_amdgcn_mfma_f32_16x16x32_bf16(a, b_frag[ks], acc, 0, 0, 0);
            }
            const float4 bias = *reinterpret_cast<const float4*>(b_hid + c * 16 + qd * 4);
            float v0 = acc[0] + bias.x, v1 = acc[1] + bias.y,
                  v2 = acc[2] + bias.z, v3 = acc[3] + bias.w;
            v0 = fmaxf(v0, ALPHA * v0); v1 = fmaxf(v1, ALPHA * v1);
            v2 = fmaxf(v2, ALPHA * v2); v3 = fmaxf(v3, ALPHA * v3);
            float4 o; o.x = v0; o.y = v1; o.z = v2; o.w = v3;
            if (node < N_NODES)                // last bucket has only 16 nodes
                *reinterpret_cast<float4*>(
                    &out[(size_t)node * HID_DIM + c * 16 + qd * 4]) = o;
        }
    }
}

extern "C" void kernel_launch(void* const* d_in, const int* in_sizes, int n_in,
                              void* d_out, int out_size, void* d_ws, size_t ws_size,
                              hipStream_t stream)
{
    const float* h_n   = (const float*)d_in[0];
    const float* h_e   = (const float*)d_in[1];
    const int*   src   = (const int*)d_in[2];
    const int*   dst   = (const int*)d_in[3];
    const float* W_msg = (const float*)d_in[4];
    const float* b_msg = (const float*)d_in[5];
    const float* W_hid = (const float*)d_in[6];
    const float* b_hid = (const float*)d_in[7];
    float* out = (float*)d_out;

    char* ws = (char*)d_ws;
    u16* hn_bf  = (u16*)(ws + 0);                    //  6,400,000 B
    u16* Wm_bf  = (u16*)(ws + 6400000);              //     51,200 B
    u16* Wh_bf  = (u16*)(ws + 6451200);              //    100,352 B
    int* cursor = (int*)(ws + 6551552);              //    100,032 B (1563 x 16 ints)
    u64* pack   = (u64*)(ws + 6651584);              //  6,402,048 B (~13.1 MB total)

    hipMemsetAsync(cursor, 0, (size_t)NBKT * CURSOR_PAD * sizeof(int), stream);
    cvt_scatter<<<CVT_BLKS + SCAT_BLKS, 256, 0, stream>>>(
        h_n, W_msg, W_hid, src, dst, hn_bf, Wm_bf, Wh_bf, cursor, pack);
    fused_kernel<<<NBKT, 256, 0, stream>>>(
        hn_bf, h_e, pack, cursor, Wm_bf, b_msg, Wh_bf, b_hid, out);
}

// Round 8
// 273.594 us; speedup vs baseline: 1.7604x; 1.0406x over previous
//
#include <hip/hip_runtime.h>

#define N_NODES 50000
#define N_EDGES 500000
#define D_NODE 64
#define D_EDGE 32
#define MSG_DIM 160
#define HID_DIM 224
#define ALPHA 0.01f

#define FNB 16          // nodes per fused block (50000 = 3125 * 16 exactly)
#define NBKT 3125       // node buckets = fused grid size
#define BKT_CAP 256     // fixed capacity per bucket (mean 160, +7.6 sigma headroom)
#define A_STRIDE 168    // 160 + 8 pad (shorts) -> conflict-free b128 frag reads
#define CURSOR_PAD 16   // ints per bucket cursor (64B line -> no line contention)
#define CVT_BLKS 3200   // ceil(818944/256)
#define SCAT_BLKS 1954  // ceil(500000/256)

typedef unsigned short u16;
typedef unsigned long long u64;
typedef short short8 __attribute__((ext_vector_type(8)));
typedef float float4v __attribute__((ext_vector_type(4)));

static __device__ __forceinline__ u16 f2bf(float f) {
    unsigned int u = __float_as_uint(f);
    u += 0x7fffu + ((u >> 16) & 1u);   // round-to-nearest-even
    return (u16)(u >> 16);
}

// fused: bf16 conversion of h_n/W_msg/W_hid (blocks 0..3199) + direct
// fixed-capacity bucket scatter (blocks 3200..). No histogram, no scan.
__global__ __launch_bounds__(256) void cvt_scatter(const float* __restrict__ h_n,
                                                   const float* __restrict__ W_msg,
                                                   const float* __restrict__ W_hid,
                                                   const int* __restrict__ src,
                                                   const int* __restrict__ dst,
                                                   u16* __restrict__ hn_bf,
                                                   u16* __restrict__ Wm_bf,
                                                   u16* __restrict__ Wh_bf,
                                                   int* __restrict__ cursor,
                                                   u64* __restrict__ pack) {
    const int b = blockIdx.x;
    if (b < CVT_BLKS) {
        int i = b * 256 + threadIdx.x;
        const float* in; u16* outp; int j;
        if (i < 800000)      { in = h_n;   outp = hn_bf; j = i; }
        else if (i < 806400) { in = W_msg; outp = Wm_bf; j = i - 800000; }
        else if (i < 818944) { in = W_hid; outp = Wh_bf; j = i - 806400; }
        else return;
        float4 v = reinterpret_cast<const float4*>(in)[j];
        ushort4 o;
        o.x = f2bf(v.x); o.y = f2bf(v.y); o.z = f2bf(v.z); o.w = f2bf(v.w);
        reinterpret_cast<ushort4*>(outp)[j] = o;
    } else {
        int e = (b - CVT_BLKS) * 256 + threadIdx.x;
        if (e < N_EDGES) {
            int d = dst[e];
            int bk = d >> 4;
            int idx = atomicAdd(&cursor[bk * CURSOR_PAD], 1);
            if (idx < BKT_CAP)   // memory-safety guard; statistically never taken
                pack[(size_t)bk * BKT_CAP + idx] =
                    ((u64)e << 34) | ((u64)d << 17) | (u64)src[e];
        }
    }
}

// ---------------- fused kernel: msg GEMM -> MFMA-based segment reduce -> update GEMM
// R0/R1 proven structure (FNB=16, direct staging, 2 barriers/tile), with the
// per-chunk LDS transpose buffer (MT) replaced by an IN-REGISTER transpose:
// the build-MFMA output M[e][f] maps to the reduce B-operand by a fixed lane
// permutation (same l15 column, cross-qd) -> 16 __shfl (ds_bpermute crossbar,
// conflict-free, no lgkmcnt round-trip) + 8 cndmask per chunk. Removes MT's
// 9.2KB LDS, its write->wait->read serial chain, and its bank conflicts.
// s_setprio(1) wraps each chunk's MFMA cluster (T5: blocks are independent /
// phase-staggered here - the attn-positive regime).
__global__ __launch_bounds__(256) void fused_kernel(
    const u16* __restrict__ hn_bf, const float* __restrict__ h_e,
    const u64* __restrict__ pack, const int* __restrict__ cursor,
    const u16* __restrict__ Wm_bf, const float* __restrict__ b_msg,
    const u16* __restrict__ Wh_bf, const float* __restrict__ b_hid,
    float* __restrict__ out)
{
    __shared__ alignas(16) u16 X_lds[64 * A_STRIDE];        // 21504 B (Xb in ph2)
    __shared__ alignas(16) u16 dst16[64];                   //   128 B -> ~21.6 KB

    const int tid = threadIdx.x;
    const int n0 = blockIdx.x * FNB;
    const int p_begin = blockIdx.x * BKT_CAP;
    int ecnt = cursor[blockIdx.x * CURSOR_PAD];
    if (ecnt > BKT_CAP) ecnt = BKT_CAP;
    const int p_end = p_begin + ecnt;

    const int wave = tid >> 6, lane = tid & 63;
    const int qd = lane >> 4, l15 = lane & 15;
    const int e_loc = tid >> 2, j4 = tid & 3;

    // transpose permutation constants (see header comment)
    const int srcA = ((qd & 1) * 2) * 16 + l15;    // source lane for j 0..3
    const int srcB = srcA + 16;                    // source lane for j 4..7
    const bool hi2 = (qd >> 1) != 0;               // selects s-pair element

    // chunk ownership: wave w owns chunks {w, w+4, w+8} (<10)
    const int nchunk = (wave < 2) ? 3 : 2;
    float biasv[3];
#pragma unroll
    for (int ci = 0; ci < 3; ++ci) {
        const int c = wave + ci * 4;
        biasv[ci] = (c < 10) ? b_msg[c * 16 + l15] : 0.f;
    }
    float4v m_acc[3] = {{0,0,0,0},{0,0,0,0},{0,0,0,0}};

    // ---------------- phase 1: edge tiles ----------------
    for (int p0 = p_begin; p0 < p_end; p0 += 64) {
        {   // stage 64 bucketed edges x 160 bf16 (4 threads per edge)
            int pp = p0 + e_loc;
            const bool padE = (pp >= p_end); if (padE) pp = p_end - 1;
            const u64 pk = pack[pp];
            const int s  = (int)(pk & 0x1FFFF);
            const int d  = (int)((pk >> 17) & 0x1FFFF);
            const int eo = (int)(pk >> 34);
            if (j4 == 0) dst16[e_loc] = padE ? (u16)0xFFFFu : (u16)(d - n0);
            const uint4* srow = reinterpret_cast<const uint4*>(hn_bf + (size_t)s * D_NODE);
            const uint4* drow = reinterpret_cast<const uint4*>(hn_bf + (size_t)d * D_NODE);
            uint4* Arow = reinterpret_cast<uint4*>(&X_lds[e_loc * A_STRIDE]);
            Arow[j4 * 2]     = srow[j4 * 2];        // bf16 [0,64): h_n[src]
            Arow[j4 * 2 + 1] = srow[j4 * 2 + 1];
            Arow[8 + j4 * 2]     = drow[j4 * 2];    // bf16 [64,128): h_n[dst]
            Arow[8 + j4 * 2 + 1] = drow[j4 * 2 + 1];
            const float4* he = reinterpret_cast<const float4*>(h_e + (size_t)eo * D_EDGE);
            float4 p = he[j4 * 2], q = he[j4 * 2 + 1];
            ushort4 lo, hi;
            lo.x = f2bf(p.x); lo.y = f2bf(p.y); lo.z = f2bf(p.z); lo.w = f2bf(p.w);
            hi.x = f2bf(q.x); hi.y = f2bf(q.y); hi.z = f2bf(q.z); hi.w = f2bf(q.w);
            ushort4* Aus = reinterpret_cast<ushort4*>(Arow);
            Aus[32 + j4 * 2]     = lo;             // bf16 [128,160): h_e
            Aus[32 + j4 * 2 + 1] = hi;
        }
        __syncthreads();   // stage visible

        // x-frags for ALL 64 edges (A operand: lane=edge row, k=qd*8+j)
        short8 xf[4][5];
#pragma unroll
        for (int s = 0; s < 4; ++s)
#pragma unroll
            for (int ks = 0; ks < 5; ++ks)
                xf[s][ks] = *reinterpret_cast<const short8*>(
                    &X_lds[(s * 16 + l15) * A_STRIDE + ks * 32 + qd * 8]);

        // selection frags S[n=l15][e=fi*32+qd*8+j] (bf16 1.0 / 0.0)
        short8 a2[2];
#pragma unroll
        for (int fi = 0; fi < 2; ++fi) {
            short8 dv = *reinterpret_cast<const short8*>(&dst16[fi * 32 + qd * 8]);
            short8 t;
#pragma unroll
            for (int j = 0; j < 8; ++j)
                t[j] = (short)(((int)(u16)dv[j] == l15) ? 0x3F80 : 0);
            a2[fi] = t;
        }
        __syncthreads();   // all frag reads done -> next stage may overwrite

        // MFMA chunk phase
        for (int ci = 0; ci < nchunk; ++ci) {
            const int c = wave + ci * 4;
            const int fbase = c * 16;
            short8 wf[5];
#pragma unroll
            for (int ks = 0; ks < 5; ++ks)       // W rows from L1/L2 (hot)
                wf[ks] = *reinterpret_cast<const short8*>(
                    Wm_bf + (size_t)(fbase + l15) * MSG_DIM + ks * 32 + qd * 8);
            const float bias = biasv[ci];
            // build: M[e = s*16 + qd*4 + r][f = fbase + l15], packed bf16x2
            int mlo[4], mhi[4];
            __builtin_amdgcn_s_setprio(1);
#pragma unroll
            for (int s = 0; s < 4; ++s) {        // 16-edge subtiles
                float4v acc = {0.f, 0.f, 0.f, 0.f};
#pragma unroll
                for (int ks = 0; ks < 5; ++ks)
                    acc = __builtin_amdgcn_mfma_f32_16x16x32_bf16(xf[s][ks], wf[ks], acc, 0, 0, 0);
                // bias + leaky (leaky == max(x, a*x))
                float v0 = acc[0] + bias, v1 = acc[1] + bias,
                      v2 = acc[2] + bias, v3 = acc[3] + bias;
                v0 = fmaxf(v0, ALPHA * v0); v1 = fmaxf(v1, ALPHA * v1);
                v2 = fmaxf(v2, ALPHA * v2); v3 = fmaxf(v3, ALPHA * v3);
                mlo[s] = (int)((unsigned)f2bf(v0) | ((unsigned)f2bf(v1) << 16));
                mhi[s] = (int)((unsigned)f2bf(v2) | ((unsigned)f2bf(v3) << 16));
            }
            // in-register transpose + reduce: m_acc += S x M
            // b2_fi[j] = M[fi*32 + qd*8 + j][fbase + l15]
            //   source array s = fi*2 + (qd>>1); source lane = srcA (j<4) / srcB
#pragma unroll
            for (int fi = 0; fi < 2; ++fi) {
                const int s0 = fi * 2, s1 = fi * 2 + 1;
                int aL0 = __shfl(mlo[s0], srcA), aL1 = __shfl(mlo[s1], srcA);
                int aH0 = __shfl(mhi[s0], srcA), aH1 = __shfl(mhi[s1], srcA);
                int bL0 = __shfl(mlo[s0], srcB), bL1 = __shfl(mlo[s1], srcB);
                int bH0 = __shfl(mhi[s0], srcB), bH1 = __shfl(mhi[s1], srcB);
                uint4 t;
                t.x = (unsigned)(hi2 ? aL1 : aL0);   // j 0..1  (r0,r1 from srcA)
                t.y = (unsigned)(hi2 ? aH1 : aH0);   // j 2..3  (r2,r3 from srcA)
                t.z = (unsigned)(hi2 ? bL1 : bL0);   // j 4..5  (r0,r1 from srcB)
                t.w = (unsigned)(hi2 ? bH1 : bH0);   // j 6..7  (r2,r3 from srcB)
                short8 b2 = *reinterpret_cast<short8*>(&t);
                m_acc[ci] = __builtin_amdgcn_mfma_f32_16x16x32_bf16(a2[fi], b2, m_acc[ci], 0, 0, 0);
            }
            __builtin_amdgcn_s_setprio(0);
        }
    }
    __syncthreads();       // phase-1 X_lds use complete

    // ---------------- phase 2: write m_acc -> bf16 LDS, update GEMM ----------
    u16* Xb = X_lds;       // reuse as [16 nodes][A_STRIDE] bf16
    for (int ci = 0; ci < nchunk; ++ci) {
        const int c = wave + ci * 4;
#pragma unroll
        for (int r = 0; r < 4; ++r)            // D[n=qd*4+r][f=c*16+l15]
            Xb[(qd * 4 + r) * A_STRIDE + c * 16 + l15] = f2bf(m_acc[ci][r]);
    }
    __syncthreads();

    const int node = n0 + l15;                 // exact (50000 = 3125*16)
    short8 b_frag[7];
#pragma unroll
    for (int ks = 0; ks < 5; ++ks)             // k in [0,160): m_sum (bf16)
        b_frag[ks] = *reinterpret_cast<const short8*>(
            &Xb[l15 * A_STRIDE + ks * 32 + qd * 8]);
#pragma unroll
    for (int ks = 5; ks < 7; ++ks)             // k in [160,224): h_n (bf16)
        b_frag[ks] = *reinterpret_cast<const short8*>(
            hn_bf + (size_t)node * D_NODE + (ks - 5) * 32 + qd * 8);

    for (int c = wave; c < 14; c += 4) {       // waves split 14 feature chunks
        float4v acc = {0.f, 0.f, 0.f, 0.f};
#pragma unroll
        for (int ks = 0; ks < 7; ++ks) {
            short8 a = *reinterpret_cast<const short8*>(
                Wh_bf + (size_t)(c * 16 + l15) * HID_DIM + ks * 32 + qd * 8);
            acc = __builtin_amdgcn_mfma_f32_16x16x32_bf16(a, b_frag[ks], acc, 0, 0, 0);
        }
        const float4 bias = *reinterpret_cast<const float4*>(b_hid + c * 16 + qd * 4);
        float v0 = acc[0] + bias.x, v1 = acc[1] + bias.y,
              v2 = acc[2] + bias.z, v3 = acc[3] + bias.w;
        v0 = fmaxf(v0, ALPHA * v0); v1 = fmaxf(v1, ALPHA * v1);
        v2 = fmaxf(v2, ALPHA * v2); v3 = fmaxf(v3, ALPHA * v3);
        float4 o; o.x = v0; o.y = v1; o.z = v2; o.w = v3;
        *reinterpret_cast<float4*>(&out[(size_t)node * HID_DIM + c * 16 + qd * 4]) = o;
    }
}

extern "C" void kernel_launch(void* const* d_in, const int* in_sizes, int n_in,
                              void* d_out, int out_size, void* d_ws, size_t ws_size,
                              hipStream_t stream)
{
    const float* h_n   = (const float*)d_in[0];
    const float* h_e   = (const float*)d_in[1];
    const int*   src   = (const int*)d_in[2];
    const int*   dst   = (const int*)d_in[3];
    const float* W_msg = (const float*)d_in[4];
    const float* b_msg = (const float*)d_in[5];
    const float* W_hid = (const float*)d_in[6];
    const float* b_hid = (const float*)d_in[7];
    float* out = (float*)d_out;

    char* ws = (char*)d_ws;
    u16* hn_bf  = (u16*)(ws + 0);                    //  6,400,000 B
    u16* Wm_bf  = (u16*)(ws + 6400000);              //     51,200 B
    u16* Wh_bf  = (u16*)(ws + 6451200);              //    100,352 B
    int* cursor = (int*)(ws + 6551552);              //    200,000 B (3125 x 16 ints)
    u64* pack   = (u64*)(ws + 6751552);              //  6,400,000 B (~13.2 MB total)

    hipMemsetAsync(cursor, 0, (size_t)NBKT * CURSOR_PAD * sizeof(int), stream);
    cvt_scatter<<<CVT_BLKS + SCAT_BLKS, 256, 0, stream>>>(
        h_n, W_msg, W_hid, src, dst, hn_bf, Wm_bf, Wh_bf, cursor, pack);
    fused_kernel<<<NBKT, 256, 0, stream>>>(
        hn_bf, h_e, pack, cursor, Wm_bf, b_msg, Wh_bf, b_hid, out);
}